// Round 8
// baseline (198.871 us; speedup 1.0000x reference)
//
#include <hip/hip_runtime.h>

// (B,T,C)=(2,2048,1024), NH=16, NKV=4, HD=64, VEC=32
typedef __bf16 bf16x8 __attribute__((ext_vector_type(8)));
typedef __bf16 bf16x4 __attribute__((ext_vector_type(4)));
typedef float f32x4 __attribute__((ext_vector_type(4)));

__device__ inline float tof(float v) { return v; }
__device__ inline float tof(__bf16 v) { return (float)v; }

__device__ inline bf16x8 load8(const __bf16* p) { return *(const bf16x8*)p; }
__device__ inline bf16x8 load8(const float* p) {
    const float4 a = *(const float4*)p;
    const float4 b = *(const float4*)(p + 4);
    bf16x8 r;
    r[0] = (__bf16)a.x; r[1] = (__bf16)a.y; r[2] = (__bf16)a.z; r[3] = (__bf16)a.w;
    r[4] = (__bf16)b.x; r[5] = (__bf16)b.y; r[6] = (__bf16)b.z; r[7] = (__bf16)b.w;
    return r;
}

// async global->LDS, 16B per lane (dest = wave-uniform base + lane*16)
__device__ __forceinline__ void cp16(__bf16* lds, const __bf16* g) {
    __builtin_amdgcn_global_load_lds((__attribute__((address_space(1))) void*)g,
                                     (__attribute__((address_space(3))) void*)lds,
                                     16, 0, 0);
}

// ---------------------------------------------------------------------------
// Kernel 0: dtype sniffer (bf16 vs fp32 input buffers)
// ---------------------------------------------------------------------------
__global__ void sniff_kernel(const unsigned short* __restrict__ xs, int* flag) {
    int tid = threadIdx.x;
    int bad = 0;
    for (int i = tid; i < 512; i += 64) {
        unsigned int f = ((unsigned int)xs[i]) << 16;
        float v = __uint_as_float(f);
        float a = fabsf(v);
        if (!(a <= 1e4f) || (a != 0.f && a < 1e-6f)) bad++;
    }
    bad += __shfl_xor(bad, 1);  bad += __shfl_xor(bad, 2);
    bad += __shfl_xor(bad, 4);  bad += __shfl_xor(bad, 8);
    bad += __shfl_xor(bad, 16); bad += __shfl_xor(bad, 32);
    if (tid == 0) *flag = (bad > 32) ? 1 : 0;
}

// ---------------------------------------------------------------------------
// Kernel 1: prep — convert x/ve/cos/sin/Wgate, transpose weights to B^T bf16.
// Grid: 3265. [0,2625) convert, [2625,3265) transpose. (gate moved into qkv)
// ---------------------------------------------------------------------------
template <typename T>
__device__ __forceinline__ void prep_body(
    const T* __restrict__ x, const T* __restrict__ ve,
    const T* __restrict__ cosp, const T* __restrict__ sinp,
    const T* __restrict__ Wq, const T* __restrict__ Wk,
    const T* __restrict__ Wv, const T* __restrict__ Wp, const T* __restrict__ Wg,
    __bf16* __restrict__ xb, __bf16* __restrict__ veb,
    float* __restrict__ cosf_, float* __restrict__ sinf_,
    __bf16* __restrict__ WqT, __bf16* __restrict__ WkT,
    __bf16* __restrict__ WvT, __bf16* __restrict__ WpT,
    __bf16* __restrict__ wgb, __bf16* tile)
{
    const int b = blockIdx.x, tid = threadIdx.x;

    if (b < 2625) {
        int g = b * 256 + tid;
        if (g < 524288) {
            *(bf16x8*)(xb + (size_t)g * 8) = load8(x + (size_t)g * 8);
        } else if (g < 655360) {
            int gg = g - 524288;
            *(bf16x8*)(veb + (size_t)gg * 8) = load8(ve + (size_t)gg * 8);
        } else if (g < 663552) {
            int gg = g - 655360;
            const T* s = cosp + (size_t)gg * 8; float* d = cosf_ + (size_t)gg * 8;
#pragma unroll
            for (int j = 0; j < 8; ++j) d[j] = tof(s[j]);
        } else if (g < 671744) {
            int gg = g - 663552;
            const T* s = sinp + (size_t)gg * 8; float* d = sinf_ + (size_t)gg * 8;
#pragma unroll
            for (int j = 0; j < 8; ++j) d[j] = tof(s[j]);
        } else if (g < 671760) {
            int gg = g - 671744;
            const T* s = Wg + (size_t)gg * 8; __bf16* d = wgb + (size_t)gg * 8;
#pragma unroll
            for (int j = 0; j < 8; ++j) d[j] = (__bf16)tof(s[j]);
        }
    } else {                              // 64x64 tile transpose
        int idx = b - 2625;
        const T* src; __bf16* dst; int C;
        if (idx < 256)      { src = Wq; dst = WqT; C = 1024; }
        else if (idx < 320) { src = Wk; dst = WkT; C = 256;  idx -= 256; }
        else if (idx < 384) { src = Wv; dst = WvT; C = 256;  idx -= 320; }
        else                { src = Wp; dst = WpT; C = 1024; idx -= 384; }
        const int ctiles = C >> 6;
        const int r0 = (idx / ctiles) * 64, c0 = (idx % ctiles) * 64;
#pragma unroll
        for (int i = 0; i < 2; ++i) {
            int c = tid + i * 256, ir = c >> 3, ic = (c & 7) * 8;
            *(bf16x8*)(&tile[ir * 72 + ic]) = load8(src + (size_t)(r0 + ir) * C + c0 + ic);
        }
        __syncthreads();
#pragma unroll
        for (int i = 0; i < 2; ++i) {
            int c = tid + i * 256, orr = c >> 3, okc = (c & 7) * 8;
            bf16x8 v;
#pragma unroll
            for (int j = 0; j < 8; ++j) v[j] = tile[(okc + j) * 72 + orr];
            *(bf16x8*)(dst + (size_t)(c0 + orr) * 1024 + r0 + okc) = v;
        }
    }
}

__global__ __launch_bounds__(256) void prep_kernel(
    const void* x, const void* ve, const void* cosp, const void* sinp,
    const void* Wq, const void* Wk, const void* Wv, const void* Wp, const void* Wg,
    __bf16* xb, __bf16* veb, float* cosf_, float* sinf_,
    __bf16* WqT, __bf16* WkT, __bf16* WvT, __bf16* WpT,
    __bf16* wgb, const int* __restrict__ flag)
{
    __shared__ __bf16 tile[64 * 72];
    if (*flag) {
        prep_body<float>((const float*)x, (const float*)ve, (const float*)cosp,
                         (const float*)sinp, (const float*)Wq, (const float*)Wk,
                         (const float*)Wv, (const float*)Wp, (const float*)Wg,
                         xb, veb, cosf_, sinf_, WqT, WkT, WvT, WpT, wgb, tile);
    } else {
        prep_body<__bf16>((const __bf16*)x, (const __bf16*)ve, (const __bf16*)cosp,
                          (const __bf16*)sinp, (const __bf16*)Wq, (const __bf16*)Wk,
                          (const __bf16*)Wv, (const __bf16*)Wp, (const __bf16*)Wg,
                          xb, veb, cosf_, sinf_, WqT, WkT, WvT, WpT, wgb, tile);
    }
}

// ---------------------------------------------------------------------------
// Kernel 2: QKV GEMM, 128x64 tiles (one head per block), wave = 32 rows x 64.
// Gate computed in-kernel via MFMA at kk==0 (A-frags hold x[:,0:32] = VEC).
// V written TRANSPOSED: vT[b][kvh][d][t]. Grid: (32, 24).
// ---------------------------------------------------------------------------
__global__ __launch_bounds__(256) void qkv_kernel(
    const __bf16* __restrict__ xb,
    const __bf16* __restrict__ WqT, const __bf16* __restrict__ WkT,
    const __bf16* __restrict__ WvT, const __bf16* __restrict__ veb,
    const float* __restrict__ cosf_, const float* __restrict__ sinf_,
    const __bf16* __restrict__ wgb,
    __bf16* __restrict__ qo, __bf16* __restrict__ ko, __bf16* __restrict__ vTo)
{
    const int row0 = blockIdx.x * 128;
    const int cb = blockIdx.y;
    const __bf16* BT; int col0, h, mode;
    if (cb < 16)      { BT = WqT; col0 = cb * 64;        h = cb;      mode = 0; }
    else if (cb < 20) { BT = WkT; col0 = (cb - 16) * 64; h = cb - 16; mode = 1; }
    else              { BT = WvT; col0 = (cb - 20) * 64; h = cb - 20; mode = 2; }

    __shared__ __align__(16) __bf16 As[128 * 32];
    __shared__ __align__(16) __bf16 Bs[64 * 32];

    const int tid  = threadIdx.x;
    const int w    = tid >> 6;
    const int lane = tid & 63;
    const int quad = lane >> 4;
    const int l15  = lane & 15;
    const int wr   = w * 32;

    f32x4 acc[2][4];
#pragma unroll
    for (int mi = 0; mi < 2; ++mi)
#pragma unroll
        for (int nj = 0; nj < 4; ++nj) acc[mi][nj] = (f32x4){0.f, 0.f, 0.f, 0.f};

    // gate B-fragment: Wg[k=quad*8+j][n=l15], cols >=4 zero
    bf16x8 wgB;
#pragma unroll
    for (int j = 0; j < 8; ++j) wgB[j] = (__bf16)0.f;
    if (mode == 2 && l15 < 4) {
#pragma unroll
        for (int j = 0; j < 8; ++j) wgB[j] = wgb[(quad * 8 + j) * 4 + l15];
    }
    f32x4 zacc[2];
    zacc[0] = (f32x4){0.f, 0.f, 0.f, 0.f};
    zacc[1] = (f32x4){0.f, 0.f, 0.f, 0.f};

    for (int kk = 0; kk < 1024; kk += 32) {
#pragma unroll
        for (int i = 0; i < 2; ++i) {
            int c = i * 256 + (w << 6) + lane;
            int rr = c >> 2, kc = (c & 3) << 3;
            cp16(&As[c << 3], &xb[(size_t)(row0 + rr) * 1024 + kk + kc]);
        }
        {
            int c = (w << 6) + lane;
            int rr = c >> 2, kc = (c & 3) << 3;
            cp16(&Bs[c << 3], &BT[(size_t)(col0 + rr) * 1024 + kk + kc]);
        }
        __syncthreads();
        bf16x8 a[2], bfr[4];
#pragma unroll
        for (int mi = 0; mi < 2; ++mi) a[mi]  = *(const bf16x8*)(&As[(wr + mi * 16 + l15) * 32 + quad * 8]);
#pragma unroll
        for (int nj = 0; nj < 4; ++nj) bfr[nj] = *(const bf16x8*)(&Bs[(nj * 16 + l15) * 32 + quad * 8]);
        if (mode == 2 && kk == 0) {   // gate z = x[:,0:32] @ Wg (A-frag == x k=0..31)
            zacc[0] = __builtin_amdgcn_mfma_f32_16x16x32_bf16(a[0], wgB, zacc[0], 0, 0, 0);
            zacc[1] = __builtin_amdgcn_mfma_f32_16x16x32_bf16(a[1], wgB, zacc[1], 0, 0, 0);
        }
#pragma unroll
        for (int mi = 0; mi < 2; ++mi)
#pragma unroll
            for (int nj = 0; nj < 4; ++nj)
                acc[mi][nj] = __builtin_amdgcn_mfma_f32_16x16x32_bf16(a[mi], bfr[nj], acc[mi][nj], 0, 0, 0);
        __syncthreads();
    }

    if (mode < 2) {
        __bf16* dst = (mode == 0) ? qo : ko;
        const int nh = (mode == 0) ? 16 : 4;
#pragma unroll
        for (int mi = 0; mi < 2; ++mi) {
#pragma unroll
            for (int r = 0; r < 4; ++r) {
                int row = row0 + wr + mi * 16 + quad * 4 + r;
                int b = row >> 11, t = row & 2047;
                float c0 = cosf_[t * 32 + l15];
                float c1 = cosf_[t * 32 + 16 + l15];
                float s0 = sinf_[t * 32 + l15];
                float s1 = sinf_[t * 32 + 16 + l15];
                float v0 =  c0 * acc[mi][0][r] + s0 * acc[mi][2][r];
                float v1 =  c1 * acc[mi][1][r] + s1 * acc[mi][3][r];
                float v2 = -s0 * acc[mi][0][r] + c0 * acc[mi][2][r];
                float v3 = -s1 * acc[mi][1][r] + c1 * acc[mi][3][r];
                float ss = v0 * v0 + v1 * v1 + v2 * v2 + v3 * v3;
                ss += __shfl_xor(ss, 1); ss += __shfl_xor(ss, 2);
                ss += __shfl_xor(ss, 4); ss += __shfl_xor(ss, 8);
                float sc = rsqrtf(ss * (1.f / 64.f) + 1.1920929e-7f);
                size_t base = (((size_t)b * nh + h) * 2048 + t) * 64;
                dst[base + 0 * 16 + l15] = (__bf16)(v0 * sc);
                dst[base + 1 * 16 + l15] = (__bf16)(v1 * sc);
                dst[base + 2 * 16 + l15] = (__bf16)(v2 * sc);
                dst[base + 3 * 16 + l15] = (__bf16)(v3 * sc);
            }
        }
    } else {
        // vT[(b*4+h)*64 + d][t], packed 4 consecutive t per store
#pragma unroll
        for (int mi = 0; mi < 2; ++mi) {
            int rowb = row0 + wr + mi * 16 + quad * 4;
            int b = rowb >> 11, t0 = rowb & 2047;
            float gg[4];
#pragma unroll
            for (int r = 0; r < 4; ++r) {
                float zv = __shfl(zacc[mi][r], quad * 16 + h);  // col h of z row
                gg[r] = 2.f / (1.f + __expf(-zv));
            }
#pragma unroll
            for (int nj = 0; nj < 4; ++nj) {
                int d = nj * 16 + l15;
                bf16x4 pack;
#pragma unroll
                for (int r = 0; r < 4; ++r) {
                    int row = rowb + r;
                    float val = acc[mi][nj][r] + gg[r] * tof(veb[(size_t)row * 256 + h * 64 + d]);
                    pack[r] = (__bf16)val;
                }
                size_t a = (((size_t)b * 4 + h) * 64 + d) * 2048 + t0;
                *(bf16x4*)(&vTo[a]) = pack;
            }
        }
    }
}

// ---------------------------------------------------------------------------
// Kernel 3: sliding-window causal GQA flash attention, 64 q-rows per block.
// cp16 XOR-swizzled K/V^T staging, double-buffered, one barrier per tile.
// LDS 41.2KB -> 3 blocks/CU; grid (32,16,2) = 1024 blocks = 12 waves/CU.
// ---------------------------------------------------------------------------
__global__ __launch_bounds__(256) void attn_kernel(
    const __bf16* __restrict__ qg, const __bf16* __restrict__ kg,
    const __bf16* __restrict__ vTg, __bf16* __restrict__ yo,
    const int* __restrict__ winp)
{
    const int q0 = blockIdx.x * 64;
    const int hh = blockIdx.y, b = blockIdx.z;
    const int kvh = hh >> 2;
    const int W = winp[0];

    const int tid  = threadIdx.x;
    const int w    = tid >> 6;
    const int lane = tid & 63;
    const int quad = lane >> 4;
    const int l15  = lane & 15;

    __shared__ __align__(16) __bf16 Ks[2][64 * 64];   // [t][d], XOR-swizzled
    __shared__ __align__(16) __bf16 Vt[2][64 * 64];   // [d][t], XOR-swizzled
    __shared__ __align__(16) __bf16 Ps[4][16 * 72];   // per-wave P (16 q-rows)

    const size_t qb = (((size_t)b * 16 + hh) * 2048 + q0 + w * 16 + l15) * 64;
    bf16x8 qf0 = *(const bf16x8*)(&qg[qb + quad * 8]);
    bf16x8 qf1 = *(const bf16x8*)(&qg[qb + 32 + quad * 8]);

    f32x4 oacc[4];
    float lsum[4];
#pragma unroll
    for (int n = 0; n < 4; ++n) { oacc[n] = (f32x4){0.f, 0.f, 0.f, 0.f}; lsum[n] = 0.f; }

    const int lo = q0 - W;
    const int kt_lo = lo > 0 ? (lo >> 6) : 0;
    const int kt_hi = q0 >> 6;
    const size_t kvbase = ((size_t)b * 4 + kvh) * 2048 * 64;

    auto stage = [&](int buf, int k0) {
#pragma unroll
        for (int i = 0; i < 2; ++i) {
            int c = i * 256 + tid;
            int rr = c >> 3;
            int jj = (c & 7) ^ (rr & 7);
            cp16(&Ks[buf][c * 8], &kg[kvbase + (size_t)(k0 + rr) * 64 + jj * 8]);
            cp16(&Vt[buf][c * 8], &vTg[kvbase + (size_t)rr * 2048 + k0 + jj * 8]);
        }
    };

    stage(0, kt_lo * 64);
    __syncthreads();

    int cur = 0;
    for (int kt = kt_lo; kt <= kt_hi; ++kt) {
        const int k0 = kt * 64;
        const bool need_mask = (k0 + 63 > q0) || (q0 + 63 - k0 > W);
        if (kt < kt_hi) stage(cur ^ 1, k0 + 64);    // async prefetch

        // QK^T
        f32x4 sacc[4];
#pragma unroll
        for (int n = 0; n < 4; ++n) sacc[n] = (f32x4){0.f, 0.f, 0.f, 0.f};
        const __bf16* Kc = &Ks[cur][0];
#pragma unroll
        for (int n = 0; n < 4; ++n) {
            int m = n * 16 + l15;
            bf16x8 b0 = *(const bf16x8*)(&Kc[m * 64 + (quad ^ (m & 7)) * 8]);
            bf16x8 b1 = *(const bf16x8*)(&Kc[m * 64 + ((4 + quad) ^ (m & 7)) * 8]);
            sacc[n] = __builtin_amdgcn_mfma_f32_16x16x32_bf16(qf0, b0, sacc[n], 0, 0, 0);
            sacc[n] = __builtin_amdgcn_mfma_f32_16x16x32_bf16(qf1, b1, sacc[n], 0, 0, 0);
        }

        // bounded-score softmax: p = exp2(s*log2e/8 - 8*log2e)
#pragma unroll
        for (int r = 0; r < 4; ++r) {
            const int row_g = q0 + w * 16 + quad * 4 + r;
#pragma unroll
            for (int n = 0; n < 4; ++n) {
                float p = exp2f(fmaf(sacc[n][r], 0.18033688f, -11.5415603f));
                if (need_mask) {
                    int col_g = k0 + n * 16 + l15;
                    bool ok = (col_g <= row_g) && (row_g - col_g <= W);
                    p = ok ? p : 0.f;
                }
                lsum[r] += p;
                Ps[w][(quad * 4 + r) * 72 + n * 16 + l15] = (__bf16)p;
            }
        }
        asm volatile("s_waitcnt lgkmcnt(0)" ::: "memory");   // wave-local Ps ordering

        // PV
        const __bf16* Vc = &Vt[cur][0];
#pragma unroll
        for (int ks = 0; ks < 2; ++ks) {
            bf16x8 pfr = *(const bf16x8*)(&Ps[w][l15 * 72 + ks * 32 + quad * 8]);
#pragma unroll
            for (int n = 0; n < 4; ++n) {
                int m = n * 16 + l15;
                bf16x8 bv = *(const bf16x8*)(&Vc[m * 64 + ((ks * 4 + quad) ^ (m & 7)) * 8]);
                oacc[n] = __builtin_amdgcn_mfma_f32_16x16x32_bf16(pfr, bv, oacc[n], 0, 0, 0);
            }
        }

        __syncthreads();   // drains prefetch cp16 + protects buffers
        cur ^= 1;
    }

#pragma unroll
    for (int r = 0; r < 4; ++r) {
        float l = lsum[r];
        l += __shfl_xor(l, 1); l += __shfl_xor(l, 2);
        l += __shfl_xor(l, 4); l += __shfl_xor(l, 8);
        float inv = 1.f / l;
        int t = q0 + w * 16 + quad * 4 + r;
        size_t base = ((size_t)(b * 2048 + t)) * 1024 + hh * 64;
#pragma unroll
        for (int n = 0; n < 4; ++n)
            yo[base + n * 16 + l15] = (__bf16)(oacc[n][r] * inv);
    }
}

// ---------------------------------------------------------------------------
// Kernel 4: output projection, 128x64 tiles, wave = 32x64. Grid: (32, 16).
// ---------------------------------------------------------------------------
__global__ __launch_bounds__(256) void proj_kernel(
    const __bf16* __restrict__ y, const __bf16* __restrict__ WpT,
    void* __restrict__ outp, const int* __restrict__ flag)
{
    const int isf32 = *flag;
    const int row0 = blockIdx.x * 128;
    const int col0 = blockIdx.y * 64;
    __shared__ __align__(16) __bf16 As[128 * 32];
    __shared__ __align__(16) __bf16 Bs[64 * 32];

    const int tid  = threadIdx.x;
    const int w    = tid >> 6;
    const int lane = tid & 63;
    const int quad = lane >> 4;
    const int l15  = lane & 15;
    const int wr   = w * 32;

    f32x4 acc[2][4];
#pragma unroll
    for (int mi = 0; mi < 2; ++mi)
#pragma unroll
        for (int nj = 0; nj < 4; ++nj) acc[mi][nj] = (f32x4){0.f, 0.f, 0.f, 0.f};

    for (int kk = 0; kk < 1024; kk += 32) {
#pragma unroll
        for (int i = 0; i < 2; ++i) {
            int c = i * 256 + (w << 6) + lane;
            int rr = c >> 2, kc = (c & 3) << 3;
            cp16(&As[c << 3], &y[(size_t)(row0 + rr) * 1024 + kk + kc]);
        }
        {
            int c = (w << 6) + lane;
            int rr = c >> 2, kc = (c & 3) << 3;
            cp16(&Bs[c << 3], &WpT[(size_t)(col0 + rr) * 1024 + kk + kc]);
        }
        __syncthreads();
        bf16x8 a[2], bfr[4];
#pragma unroll
        for (int mi = 0; mi < 2; ++mi) a[mi]  = *(const bf16x8*)(&As[(wr + mi * 16 + l15) * 32 + quad * 8]);
#pragma unroll
        for (int nj = 0; nj < 4; ++nj) bfr[nj] = *(const bf16x8*)(&Bs[(nj * 16 + l15) * 32 + quad * 8]);
#pragma unroll
        for (int mi = 0; mi < 2; ++mi)
#pragma unroll
            for (int nj = 0; nj < 4; ++nj)
                acc[mi][nj] = __builtin_amdgcn_mfma_f32_16x16x32_bf16(a[mi], bfr[nj], acc[mi][nj], 0, 0, 0);
        __syncthreads();
    }

#pragma unroll
    for (int mi = 0; mi < 2; ++mi)
#pragma unroll
        for (int r = 0; r < 4; ++r) {
            int row = row0 + wr + mi * 16 + quad * 4 + r;
            if (isf32) {
                float* out = (float*)outp;
#pragma unroll
                for (int nj = 0; nj < 4; ++nj)
                    out[(size_t)row * 1024 + col0 + nj * 16 + l15] = acc[mi][nj][r];
            } else {
                __bf16* out = (__bf16*)outp;
#pragma unroll
                for (int nj = 0; nj < 4; ++nj)
                    out[(size_t)row * 1024 + col0 + nj * 16 + l15] = (__bf16)acc[mi][nj][r];
            }
        }
}

extern "C" void kernel_launch(void* const* d_in, const int* in_sizes, int n_in,
                              void* d_out, int out_size, void* d_ws, size_t ws_size,
                              hipStream_t stream) {
    const int* win = (const int*)d_in[9];

    char* p = (char*)d_ws;
    int*    flag = (int*)p;                    p += 256;
    __bf16* q_ws = (__bf16*)p;                 p += (size_t)4194304 * 2;
    __bf16* k_ws = (__bf16*)p;                 p += (size_t)1048576 * 2;
    __bf16* vT_ws= (__bf16*)p;                 p += (size_t)1048576 * 2;
    __bf16* y_ws = (__bf16*)p;                 p += (size_t)4194304 * 2;
    __bf16* xb   = (__bf16*)p;                 p += (size_t)4194304 * 2;
    __bf16* veb  = (__bf16*)p;                 p += (size_t)1048576 * 2;
    __bf16* WqT  = (__bf16*)p;                 p += (size_t)1048576 * 2;
    __bf16* WkT  = (__bf16*)p;                 p += (size_t)262144 * 2;
    __bf16* WvT  = (__bf16*)p;                 p += (size_t)262144 * 2;
    __bf16* WpT  = (__bf16*)p;                 p += (size_t)1048576 * 2;
    float*  cosf_ = (float*)p;                 p += (size_t)65536 * 4;
    float*  sinf_ = (float*)p;                 p += (size_t)65536 * 4;
    __bf16* wgb   = (__bf16*)p;                p += 256;

    sniff_kernel<<<1, 64, 0, stream>>>((const unsigned short*)d_in[0], flag);

    prep_kernel<<<3265, 256, 0, stream>>>(
        d_in[0], d_in[1], d_in[2], d_in[3], d_in[4], d_in[5], d_in[6], d_in[7],
        d_in[8], xb, veb, cosf_, sinf_, WqT, WkT, WvT, WpT, wgb, flag);

    qkv_kernel<<<dim3(32, 24), 256, 0, stream>>>(xb, WqT, WkT, WvT, veb,
                                                 cosf_, sinf_, wgb, q_ws, k_ws, vT_ws);

    attn_kernel<<<dim3(32, 16, 2), 256, 0, stream>>>(q_ws, k_ws, vT_ws, y_ws, win);

    proj_kernel<<<dim3(32, 16), 256, 0, stream>>>(y_ws, WpT, d_out, flag);
}

// Round 9
// 198.609 us; speedup vs baseline: 1.0013x; 1.0013x over previous
//
#include <hip/hip_runtime.h>

// (B,T,C)=(2,2048,1024), NH=16, NKV=4, HD=64, VEC=32
typedef __bf16 bf16x8 __attribute__((ext_vector_type(8)));
typedef __bf16 bf16x4 __attribute__((ext_vector_type(4)));
typedef float f32x4 __attribute__((ext_vector_type(4)));

__device__ inline float tof(float v) { return v; }
__device__ inline float tof(__bf16 v) { return (float)v; }

__device__ inline bf16x8 load8(const __bf16* p) { return *(const bf16x8*)p; }
__device__ inline bf16x8 load8(const float* p) {
    const float4 a = *(const float4*)p;
    const float4 b = *(const float4*)(p + 4);
    bf16x8 r;
    r[0] = (__bf16)a.x; r[1] = (__bf16)a.y; r[2] = (__bf16)a.z; r[3] = (__bf16)a.w;
    r[4] = (__bf16)b.x; r[5] = (__bf16)b.y; r[6] = (__bf16)b.z; r[7] = (__bf16)b.w;
    return r;
}

// async global->LDS, 16B per lane (dest = wave-uniform base + lane*16)
__device__ __forceinline__ void cp16(__bf16* lds, const __bf16* g) {
    __builtin_amdgcn_global_load_lds((__attribute__((address_space(1))) void*)g,
                                     (__attribute__((address_space(3))) void*)lds,
                                     16, 0, 0);
}

// ---------------------------------------------------------------------------
// Kernel 0: dtype sniffer (bf16 vs fp32 input buffers)
// ---------------------------------------------------------------------------
__global__ void sniff_kernel(const unsigned short* __restrict__ xs, int* flag) {
    int tid = threadIdx.x;
    int bad = 0;
    for (int i = tid; i < 512; i += 64) {
        unsigned int f = ((unsigned int)xs[i]) << 16;
        float v = __uint_as_float(f);
        float a = fabsf(v);
        if (!(a <= 1e4f) || (a != 0.f && a < 1e-6f)) bad++;
    }
    bad += __shfl_xor(bad, 1);  bad += __shfl_xor(bad, 2);
    bad += __shfl_xor(bad, 4);  bad += __shfl_xor(bad, 8);
    bad += __shfl_xor(bad, 16); bad += __shfl_xor(bad, 32);
    if (tid == 0) *flag = (bad > 32) ? 1 : 0;
}

// ---------------------------------------------------------------------------
// Kernel 1: prep — convert x/ve/cos/sin/Wgate, transpose weights to B^T bf16.
// ---------------------------------------------------------------------------
template <typename T>
__device__ __forceinline__ void prep_body(
    const T* __restrict__ x, const T* __restrict__ ve,
    const T* __restrict__ cosp, const T* __restrict__ sinp,
    const T* __restrict__ Wq, const T* __restrict__ Wk,
    const T* __restrict__ Wv, const T* __restrict__ Wp, const T* __restrict__ Wg,
    __bf16* __restrict__ xb, __bf16* __restrict__ veb,
    float* __restrict__ cosf_, float* __restrict__ sinf_,
    __bf16* __restrict__ WqT, __bf16* __restrict__ WkT,
    __bf16* __restrict__ WvT, __bf16* __restrict__ WpT,
    __bf16* __restrict__ wgb, __bf16* tile)
{
    const int b = blockIdx.x, tid = threadIdx.x;

    if (b < 2625) {
        int g = b * 256 + tid;
        if (g < 524288) {
            *(bf16x8*)(xb + (size_t)g * 8) = load8(x + (size_t)g * 8);
        } else if (g < 655360) {
            int gg = g - 524288;
            *(bf16x8*)(veb + (size_t)gg * 8) = load8(ve + (size_t)gg * 8);
        } else if (g < 663552) {
            int gg = g - 655360;
            const T* s = cosp + (size_t)gg * 8; float* d = cosf_ + (size_t)gg * 8;
#pragma unroll
            for (int j = 0; j < 8; ++j) d[j] = tof(s[j]);
        } else if (g < 671744) {
            int gg = g - 663552;
            const T* s = sinp + (size_t)gg * 8; float* d = sinf_ + (size_t)gg * 8;
#pragma unroll
            for (int j = 0; j < 8; ++j) d[j] = tof(s[j]);
        } else if (g < 671760) {
            int gg = g - 671744;
            const T* s = Wg + (size_t)gg * 8; __bf16* d = wgb + (size_t)gg * 8;
#pragma unroll
            for (int j = 0; j < 8; ++j) d[j] = (__bf16)tof(s[j]);
        }
    } else {                              // 64x64 tile transpose
        int idx = b - 2625;
        const T* src; __bf16* dst; int C;
        if (idx < 256)      { src = Wq; dst = WqT; C = 1024; }
        else if (idx < 320) { src = Wk; dst = WkT; C = 256;  idx -= 256; }
        else if (idx < 384) { src = Wv; dst = WvT; C = 256;  idx -= 320; }
        else                { src = Wp; dst = WpT; C = 1024; idx -= 384; }
        const int ctiles = C >> 6;
        const int r0 = (idx / ctiles) * 64, c0 = (idx % ctiles) * 64;
#pragma unroll
        for (int i = 0; i < 2; ++i) {
            int c = tid + i * 256, ir = c >> 3, ic = (c & 7) * 8;
            *(bf16x8*)(&tile[ir * 72 + ic]) = load8(src + (size_t)(r0 + ir) * C + c0 + ic);
        }
        __syncthreads();
#pragma unroll
        for (int i = 0; i < 2; ++i) {
            int c = tid + i * 256, orr = c >> 3, okc = (c & 7) * 8;
            bf16x8 v;
#pragma unroll
            for (int j = 0; j < 8; ++j) v[j] = tile[(okc + j) * 72 + orr];
            *(bf16x8*)(dst + (size_t)(c0 + orr) * 1024 + r0 + okc) = v;
        }
    }
}

__global__ __launch_bounds__(256) void prep_kernel(
    const void* x, const void* ve, const void* cosp, const void* sinp,
    const void* Wq, const void* Wk, const void* Wv, const void* Wp, const void* Wg,
    __bf16* xb, __bf16* veb, float* cosf_, float* sinf_,
    __bf16* WqT, __bf16* WkT, __bf16* WvT, __bf16* WpT,
    __bf16* wgb, const int* __restrict__ flag)
{
    __shared__ __bf16 tile[64 * 72];
    if (*flag) {
        prep_body<float>((const float*)x, (const float*)ve, (const float*)cosp,
                         (const float*)sinp, (const float*)Wq, (const float*)Wk,
                         (const float*)Wv, (const float*)Wp, (const float*)Wg,
                         xb, veb, cosf_, sinf_, WqT, WkT, WvT, WpT, wgb, tile);
    } else {
        prep_body<__bf16>((const __bf16*)x, (const __bf16*)ve, (const __bf16*)cosp,
                          (const __bf16*)sinp, (const __bf16*)Wq, (const __bf16*)Wk,
                          (const __bf16*)Wv, (const __bf16*)Wp, (const __bf16*)Wg,
                          xb, veb, cosf_, sinf_, WqT, WkT, WvT, WpT, wgb, tile);
    }
}

// ---------------------------------------------------------------------------
// Kernel 2: QKV GEMM, 128x128 tiles (m97 geometry), wave = 64x64 quadrant.
// Gate via MFMA at kk==0. V written transposed vT[b][kvh][d][t].
// Grid: (32, 12). cb<8: q (2 heads/block); cb<10: k; else v.
// ---------------------------------------------------------------------------
__global__ __launch_bounds__(256) void qkv_kernel(
    const __bf16* __restrict__ xb,
    const __bf16* __restrict__ WqT, const __bf16* __restrict__ WkT,
    const __bf16* __restrict__ WvT, const __bf16* __restrict__ veb,
    const float* __restrict__ cosf_, const float* __restrict__ sinf_,
    const __bf16* __restrict__ wgb,
    __bf16* __restrict__ qo, __bf16* __restrict__ ko, __bf16* __restrict__ vTo)
{
    const int row0 = blockIdx.x * 128;
    const int cb = blockIdx.y;
    const __bf16* BT; int col0, mode;
    if (cb < 8)       { BT = WqT; col0 = cb * 128;        mode = 0; }
    else if (cb < 10) { BT = WkT; col0 = (cb - 8) * 128;  mode = 1; }
    else              { BT = WvT; col0 = (cb - 10) * 128; mode = 2; }

    __shared__ __align__(16) __bf16 As[128 * 32];
    __shared__ __align__(16) __bf16 Bs[128 * 32];

    const int tid  = threadIdx.x;
    const int w    = tid >> 6;
    const int lane = tid & 63;
    const int quad = lane >> 4;
    const int l15  = lane & 15;
    const int wr   = (w >> 1) * 64, wc = (w & 1) * 64;
    const int h    = (col0 + wc) >> 6;        // head: q 0..15, k/v 0..3

    f32x4 acc[4][4];
#pragma unroll
    for (int mi = 0; mi < 4; ++mi)
#pragma unroll
        for (int nj = 0; nj < 4; ++nj) acc[mi][nj] = (f32x4){0.f, 0.f, 0.f, 0.f};

    // gate B-fragment: Wg[k=quad*8+j][n=l15], cols >=4 zero
    bf16x8 wgB;
#pragma unroll
    for (int j = 0; j < 8; ++j) wgB[j] = (__bf16)0.f;
    if (mode == 2 && l15 < 4) {
#pragma unroll
        for (int j = 0; j < 8; ++j) wgB[j] = wgb[(quad * 8 + j) * 4 + l15];
    }
    f32x4 zacc[4];
#pragma unroll
    for (int mi = 0; mi < 4; ++mi) zacc[mi] = (f32x4){0.f, 0.f, 0.f, 0.f};

    for (int kk = 0; kk < 1024; kk += 32) {
#pragma unroll
        for (int i = 0; i < 2; ++i) {
            int c = i * 256 + (w << 6) + lane;
            int rr = c >> 2, kc = (c & 3) << 3;
            cp16(&As[c << 3], &xb[(size_t)(row0 + rr) * 1024 + kk + kc]);
            cp16(&Bs[c << 3], &BT[(size_t)(col0 + rr) * 1024 + kk + kc]);
        }
        __syncthreads();
        bf16x8 a[4], bfr[4];
#pragma unroll
        for (int mi = 0; mi < 4; ++mi) a[mi]  = *(const bf16x8*)(&As[(wr + mi * 16 + l15) * 32 + quad * 8]);
#pragma unroll
        for (int nj = 0; nj < 4; ++nj) bfr[nj] = *(const bf16x8*)(&Bs[(wc + nj * 16 + l15) * 32 + quad * 8]);
        if (mode == 2 && kk == 0) {   // gate z = x[:,0:32] @ Wg
#pragma unroll
            for (int mi = 0; mi < 4; ++mi)
                zacc[mi] = __builtin_amdgcn_mfma_f32_16x16x32_bf16(a[mi], wgB, zacc[mi], 0, 0, 0);
        }
#pragma unroll
        for (int mi = 0; mi < 4; ++mi)
#pragma unroll
            for (int nj = 0; nj < 4; ++nj)
                acc[mi][nj] = __builtin_amdgcn_mfma_f32_16x16x32_bf16(a[mi], bfr[nj], acc[mi][nj], 0, 0, 0);
        __syncthreads();
    }

    if (mode < 2) {
        __bf16* dst = (mode == 0) ? qo : ko;
        const int nh = (mode == 0) ? 16 : 4;
#pragma unroll
        for (int mi = 0; mi < 4; ++mi) {
#pragma unroll
            for (int r = 0; r < 4; ++r) {
                int row = row0 + wr + mi * 16 + quad * 4 + r;
                int b = row >> 11, t = row & 2047;
                float c0 = cosf_[t * 32 + l15];
                float c1 = cosf_[t * 32 + 16 + l15];
                float s0 = sinf_[t * 32 + l15];
                float s1 = sinf_[t * 32 + 16 + l15];
                float v0 =  c0 * acc[mi][0][r] + s0 * acc[mi][2][r];
                float v1 =  c1 * acc[mi][1][r] + s1 * acc[mi][3][r];
                float v2 = -s0 * acc[mi][0][r] + c0 * acc[mi][2][r];
                float v3 = -s1 * acc[mi][1][r] + c1 * acc[mi][3][r];
                float ss = v0 * v0 + v1 * v1 + v2 * v2 + v3 * v3;
                ss += __shfl_xor(ss, 1); ss += __shfl_xor(ss, 2);
                ss += __shfl_xor(ss, 4); ss += __shfl_xor(ss, 8);
                float sc = rsqrtf(ss * (1.f / 64.f) + 1.1920929e-7f);
                size_t base = (((size_t)b * nh + h) * 2048 + t) * 64;
                dst[base + 0 * 16 + l15] = (__bf16)(v0 * sc);
                dst[base + 1 * 16 + l15] = (__bf16)(v1 * sc);
                dst[base + 2 * 16 + l15] = (__bf16)(v2 * sc);
                dst[base + 3 * 16 + l15] = (__bf16)(v3 * sc);
            }
        }
    } else {
        // vT[(b*4+h)*64 + d][t], packed 4 consecutive t per store
#pragma unroll
        for (int mi = 0; mi < 4; ++mi) {
            int rowb = row0 + wr + mi * 16 + quad * 4;
            int b = rowb >> 11, t0 = rowb & 2047;
            float gg[4];
#pragma unroll
            for (int r = 0; r < 4; ++r) {
                float zv = __shfl(zacc[mi][r], quad * 16 + h);  // col h, own quad
                gg[r] = 2.f / (1.f + __expf(-zv));
            }
#pragma unroll
            for (int nj = 0; nj < 4; ++nj) {
                int d = nj * 16 + l15;
                bf16x4 pack;
#pragma unroll
                for (int r = 0; r < 4; ++r) {
                    int row = rowb + r;
                    float val = acc[mi][nj][r] + gg[r] * tof(veb[(size_t)row * 256 + h * 64 + d]);
                    pack[r] = (__bf16)val;
                }
                size_t a = (((size_t)b * 4 + h) * 64 + d) * 2048 + t0;
                *(bf16x4*)(&vTo[a]) = pack;
            }
        }
    }
}

// ---------------------------------------------------------------------------
// Kernel 3: sliding-window causal GQA flash attention (round-7 config).
// Block = 128 q-rows x 1 head, wave owns 32 rows. cp16 XOR-swizzled K/V^T,
// double-buffered, one barrier per tile. Grid: (16, 16, 2).
// ---------------------------------------------------------------------------
__global__ __launch_bounds__(256) void attn_kernel(
    const __bf16* __restrict__ qg, const __bf16* __restrict__ kg,
    const __bf16* __restrict__ vTg, __bf16* __restrict__ yo,
    const int* __restrict__ winp)
{
    const int q0 = blockIdx.x * 128;
    const int hh = blockIdx.y, b = blockIdx.z;
    const int kvh = hh >> 2;
    const int W = winp[0];

    const int tid  = threadIdx.x;
    const int w    = tid >> 6;
    const int lane = tid & 63;
    const int quad = lane >> 4;
    const int l15  = lane & 15;

    __shared__ __align__(16) __bf16 Ks[2][64 * 64];   // [t][d], XOR-swizzled
    __shared__ __align__(16) __bf16 Vt[2][64 * 64];   // [d][t], XOR-swizzled
    __shared__ __align__(16) __bf16 Ps[4][32 * 72];   // per-wave P

    bf16x8 qf[2][2];
#pragma unroll
    for (int i = 0; i < 2; ++i) {
        size_t qb = (((size_t)b * 16 + hh) * 2048 + q0 + w * 32 + i * 16 + l15) * 64;
        qf[i][0] = *(const bf16x8*)(&qg[qb + quad * 8]);
        qf[i][1] = *(const bf16x8*)(&qg[qb + 32 + quad * 8]);
    }

    f32x4 oacc[2][4];
    float lsum[2][4];
#pragma unroll
    for (int i = 0; i < 2; ++i)
#pragma unroll
        for (int n = 0; n < 4; ++n) {
            oacc[i][n] = (f32x4){0.f, 0.f, 0.f, 0.f};
            lsum[i][n] = 0.f;
        }

    const int lo = q0 - W;
    const int kt_lo = lo > 0 ? (lo >> 6) : 0;
    const int kt_hi = (q0 + 127) >> 6;
    const size_t kvbase = ((size_t)b * 4 + kvh) * 2048 * 64;

    auto stage = [&](int buf, int k0) {
#pragma unroll
        for (int i = 0; i < 2; ++i) {
            int c = i * 256 + tid;
            int rr = c >> 3;
            int jj = (c & 7) ^ (rr & 7);
            cp16(&Ks[buf][c * 8], &kg[kvbase + (size_t)(k0 + rr) * 64 + jj * 8]);
            cp16(&Vt[buf][c * 8], &vTg[kvbase + (size_t)rr * 2048 + k0 + jj * 8]);
        }
    };

    stage(0, kt_lo * 64);
    __syncthreads();

    int cur = 0;
    for (int kt = kt_lo; kt <= kt_hi; ++kt) {
        const int k0 = kt * 64;
        const bool need_mask = (k0 + 63 > q0) || (q0 + 127 - k0 > W);
        if (kt < kt_hi) stage(cur ^ 1, k0 + 64);    // async prefetch

        // QK^T
        f32x4 sacc[2][4];
#pragma unroll
        for (int i = 0; i < 2; ++i)
#pragma unroll
            for (int n = 0; n < 4; ++n) sacc[i][n] = (f32x4){0.f, 0.f, 0.f, 0.f};
        const __bf16* Kc = &Ks[cur][0];
#pragma unroll
        for (int n = 0; n < 4; ++n) {
            int m = n * 16 + l15;
            bf16x8 b0 = *(const bf16x8*)(&Kc[m * 64 + (quad ^ (m & 7)) * 8]);
            bf16x8 b1 = *(const bf16x8*)(&Kc[m * 64 + ((4 + quad) ^ (m & 7)) * 8]);
#pragma unroll
            for (int i = 0; i < 2; ++i) {
                sacc[i][n] = __builtin_amdgcn_mfma_f32_16x16x32_bf16(qf[i][0], b0, sacc[i][n], 0, 0, 0);
                sacc[i][n] = __builtin_amdgcn_mfma_f32_16x16x32_bf16(qf[i][1], b1, sacc[i][n], 0, 0, 0);
            }
        }

        // bounded-score softmax: p = exp2(s*log2e/8 - 8*log2e)
#pragma unroll
        for (int i = 0; i < 2; ++i) {
#pragma unroll
            for (int r = 0; r < 4; ++r) {
                const int row_g = q0 + w * 32 + i * 16 + quad * 4 + r;
#pragma unroll
                for (int n = 0; n < 4; ++n) {
                    float p = exp2f(fmaf(sacc[i][n][r], 0.18033688f, -11.5415603f));
                    if (need_mask) {
                        int col_g = k0 + n * 16 + l15;
                        bool ok = (col_g <= row_g) && (row_g - col_g <= W);
                        p = ok ? p : 0.f;
                    }
                    lsum[i][r] += p;
                    Ps[w][(i * 16 + quad * 4 + r) * 72 + n * 16 + l15] = (__bf16)p;
                }
            }
        }
        asm volatile("s_waitcnt lgkmcnt(0)" ::: "memory");   // wave-local Ps ordering

        // PV
        const __bf16* Vc = &Vt[cur][0];
#pragma unroll
        for (int ks = 0; ks < 2; ++ks) {
            bf16x8 pfr0 = *(const bf16x8*)(&Ps[w][l15 * 72 + ks * 32 + quad * 8]);
            bf16x8 pfr1 = *(const bf16x8*)(&Ps[w][(16 + l15) * 72 + ks * 32 + quad * 8]);
#pragma unroll
            for (int n = 0; n < 4; ++n) {
                int m = n * 16 + l15;
                bf16x8 bv = *(const bf16x8*)(&Vc[m * 64 + ((ks * 4 + quad) ^ (m & 7)) * 8]);
                oacc[0][n] = __builtin_amdgcn_mfma_f32_16x16x32_bf16(pfr0, bv, oacc[0][n], 0, 0, 0);
                oacc[1][n] = __builtin_amdgcn_mfma_f32_16x16x32_bf16(pfr1, bv, oacc[1][n], 0, 0, 0);
            }
        }

        __syncthreads();   // drains prefetch cp16 + protects buffers
        cur ^= 1;
    }

#pragma unroll
    for (int i = 0; i < 2; ++i) {
#pragma unroll
        for (int r = 0; r < 4; ++r) {
            float l = lsum[i][r];
            l += __shfl_xor(l, 1); l += __shfl_xor(l, 2);
            l += __shfl_xor(l, 4); l += __shfl_xor(l, 8);
            float inv = 1.f / l;
            int t = q0 + w * 32 + i * 16 + quad * 4 + r;
            size_t base = ((size_t)(b * 2048 + t)) * 1024 + hh * 64;
#pragma unroll
            for (int n = 0; n < 4; ++n)
                yo[base + n * 16 + l15] = (__bf16)(oacc[i][n][r] * inv);
        }
    }
}

// ---------------------------------------------------------------------------
// Kernel 4: output projection, 128x64 tiles, wave = 32x64. Grid: (32, 16).
// ---------------------------------------------------------------------------
__global__ __launch_bounds__(256) void proj_kernel(
    const __bf16* __restrict__ y, const __bf16* __restrict__ WpT,
    void* __restrict__ outp, const int* __restrict__ flag)
{
    const int isf32 = *flag;
    const int row0 = blockIdx.x * 128;
    const int col0 = blockIdx.y * 64;
    __shared__ __align__(16) __bf16 As[128 * 32];
    __shared__ __align__(16) __bf16 Bs[64 * 32];

    const int tid  = threadIdx.x;
    const int w    = tid >> 6;
    const int lane = tid & 63;
    const int quad = lane >> 4;
    const int l15  = lane & 15;
    const int wr   = w * 32;

    f32x4 acc[2][4];
#pragma unroll
    for (int mi = 0; mi < 2; ++mi)
#pragma unroll
        for (int nj = 0; nj < 4; ++nj) acc[mi][nj] = (f32x4){0.f, 0.f, 0.f, 0.f};

    for (int kk = 0; kk < 1024; kk += 32) {
#pragma unroll
        for (int i = 0; i < 2; ++i) {
            int c = i * 256 + (w << 6) + lane;
            int rr = c >> 2, kc = (c & 3) << 3;
            cp16(&As[c << 3], &y[(size_t)(row0 + rr) * 1024 + kk + kc]);
        }
        {
            int c = (w << 6) + lane;
            int rr = c >> 2, kc = (c & 3) << 3;
            cp16(&Bs[c << 3], &WpT[(size_t)(col0 + rr) * 1024 + kk + kc]);
        }
        __syncthreads();
        bf16x8 a[2], bfr[4];
#pragma unroll
        for (int mi = 0; mi < 2; ++mi) a[mi]  = *(const bf16x8*)(&As[(wr + mi * 16 + l15) * 32 + quad * 8]);
#pragma unroll
        for (int nj = 0; nj < 4; ++nj) bfr[nj] = *(const bf16x8*)(&Bs[(nj * 16 + l15) * 32 + quad * 8]);
#pragma unroll
        for (int mi = 0; mi < 2; ++mi)
#pragma unroll
            for (int nj = 0; nj < 4; ++nj)
                acc[mi][nj] = __builtin_amdgcn_mfma_f32_16x16x32_bf16(a[mi], bfr[nj], acc[mi][nj], 0, 0, 0);
        __syncthreads();
    }

#pragma unroll
    for (int mi = 0; mi < 2; ++mi)
#pragma unroll
        for (int r = 0; r < 4; ++r) {
            int row = row0 + wr + mi * 16 + quad * 4 + r;
            if (isf32) {
                float* out = (float*)outp;
#pragma unroll
                for (int nj = 0; nj < 4; ++nj)
                    out[(size_t)row * 1024 + col0 + nj * 16 + l15] = acc[mi][nj][r];
            } else {
                __bf16* out = (__bf16*)outp;
#pragma unroll
                for (int nj = 0; nj < 4; ++nj)
                    out[(size_t)row * 1024 + col0 + nj * 16 + l15] = (__bf16)acc[mi][nj][r];
            }
        }
}

extern "C" void kernel_launch(void* const* d_in, const int* in_sizes, int n_in,
                              void* d_out, int out_size, void* d_ws, size_t ws_size,
                              hipStream_t stream) {
    const int* win = (const int*)d_in[9];

    char* p = (char*)d_ws;
    int*    flag = (int*)p;                    p += 256;
    __bf16* q_ws = (__bf16*)p;                 p += (size_t)4194304 * 2;
    __bf16* k_ws = (__bf16*)p;                 p += (size_t)1048576 * 2;
    __bf16* vT_ws= (__bf16*)p;                 p += (size_t)1048576 * 2;
    __bf16* y_ws = (__bf16*)p;                 p += (size_t)4194304 * 2;
    __bf16* xb   = (__bf16*)p;                 p += (size_t)4194304 * 2;
    __bf16* veb  = (__bf16*)p;                 p += (size_t)1048576 * 2;
    __bf16* WqT  = (__bf16*)p;                 p += (size_t)1048576 * 2;
    __bf16* WkT  = (__bf16*)p;                 p += (size_t)262144 * 2;
    __bf16* WvT  = (__bf16*)p;                 p += (size_t)262144 * 2;
    __bf16* WpT  = (__bf16*)p;                 p += (size_t)1048576 * 2;
    float*  cosf_ = (float*)p;                 p += (size_t)65536 * 4;
    float*  sinf_ = (float*)p;                 p += (size_t)65536 * 4;
    __bf16* wgb   = (__bf16*)p;                p += 256;

    sniff_kernel<<<1, 64, 0, stream>>>((const unsigned short*)d_in[0], flag);

    prep_kernel<<<3265, 256, 0, stream>>>(
        d_in[0], d_in[1], d_in[2], d_in[3], d_in[4], d_in[5], d_in[6], d_in[7],
        d_in[8], xb, veb, cosf_, sinf_, WqT, WkT, WvT, WpT, wgb, flag);

    qkv_kernel<<<dim3(32, 12), 256, 0, stream>>>(xb, WqT, WkT, WvT, veb,
                                                 cosf_, sinf_, wgb, q_ws, k_ws, vT_ws);

    attn_kernel<<<dim3(16, 16, 2), 256, 0, stream>>>(q_ws, k_ws, vT_ws, y_ws, win);

    proj_kernel<<<dim3(32, 16), 256, 0, stream>>>(y_ws, WpT, d_out, flag);
}